// Round 1
// baseline (1420.512 us; speedup 1.0000x reference)
//
#include <hip/hip_runtime.h>
#include <hip/hip_bf16.h>
#include <cstddef>
#include <cstdint>

// Problem dims (fixed by setup_inputs)
#define NB   32
#define LSEQ 1024
#define HDIM 1280
#define PDIM 128

// ws layout (floats): [0,32) per-batch loss accumulators; e (32768x128); eT (32 x 128 x 1024)
#define ACC_OFF 0
#define E_OFF   256
#define ET_OFF  (256 + NB * LSEQ * PDIM)
// total ws requirement: (256 + 2*4194304)*4 B = ~33.6 MB

// ---------------------------------------------------------------------------
// k1: emb = hs @ w + b; emb /= ||emb||; store e (row-major) and eT (k-major).
// 16 rows per block, 128 threads (thread = output column).
// hs reads are wave-uniform -> scalar loads (s_load_dwordx4); w reads are
// per-lane, L2-hot (w = 640 KB). No LDS in the hot loop.
// ---------------------------------------------------------------------------
__global__ __launch_bounds__(128) void k1_proj(const float* __restrict__ hs,
                                               const float* __restrict__ pw,
                                               const float* __restrict__ pb,
                                               float* __restrict__ e,
                                               float* __restrict__ eT) {
  const int tid = threadIdx.x;          // column 0..127
  const int r0  = blockIdx.x * 16;      // global row base (never crosses batch)

  float acc[16];
#pragma unroll
  for (int r = 0; r < 16; ++r) acc[r] = 0.0f;

  for (int k0 = 0; k0 < HDIM; k0 += 4) {
    const float w0 = pw[(size_t)(k0 + 0) * PDIM + tid];
    const float w1 = pw[(size_t)(k0 + 1) * PDIM + tid];
    const float w2 = pw[(size_t)(k0 + 2) * PDIM + tid];
    const float w3 = pw[(size_t)(k0 + 3) * PDIM + tid];
#pragma unroll
    for (int r = 0; r < 16; ++r) {
      const float4 a = *(const float4*)(hs + (size_t)(r0 + r) * HDIM + k0);
      acc[r] = fmaf(a.x, w0, acc[r]);
      acc[r] = fmaf(a.y, w1, acc[r]);
      acc[r] = fmaf(a.z, w2, acc[r]);
      acc[r] = fmaf(a.w, w3, acc[r]);
    }
  }

  const float bv = pb[tid];
#pragma unroll
  for (int r = 0; r < 16; ++r) acc[r] += bv;

  // row-wise sum of squares across the 128 threads (2 waves)
  __shared__ float red[16][2];
  const int lane = tid & 63, wid = tid >> 6;
#pragma unroll
  for (int r = 0; r < 16; ++r) {
    float v = acc[r] * acc[r];
#pragma unroll
    for (int off = 32; off; off >>= 1) v += __shfl_xor(v, off, 64);
    if (lane == 0) red[r][wid] = v;
  }
  __syncthreads();

  float ev[16];
#pragma unroll
  for (int r = 0; r < 16; ++r) {
    const float nrm = red[r][0] + red[r][1];
    const float inv = 1.0f / sqrtf(nrm);
    ev[r] = acc[r] * inv;
    e[(size_t)(r0 + r) * PDIM + tid] = ev[r];
  }

  // eT[b][k][j]: thread holds column k=tid for 16 consecutive j -> 4 float4 stores
  const int bb = r0 >> 10;
  const int j0 = r0 & (LSEQ - 1);
  float* dst = eT + (size_t)bb * (PDIM * LSEQ) + (size_t)tid * LSEQ + j0;
#pragma unroll
  for (int m = 0; m < 4; ++m) {
    float4 v4;
    v4.x = ev[4 * m + 0];
    v4.y = ev[4 * m + 1];
    v4.z = ev[4 * m + 2];
    v4.w = ev[4 * m + 3];
    *(float4*)(dst + 4 * m) = v4;
  }
}

// ---------------------------------------------------------------------------
// k2: per (batch, 16-anchor tile): sim row block -> masked softmax stats ->
// per-anchor contribution atomically added to accb[b].
// Pass A: anchors via wave-uniform float4 (scalar pipe), eT per-lane coalesced.
// S tile kept in LDS (exactly 64 KB). Pass B: 16 threads per anchor.
// ---------------------------------------------------------------------------
__global__ __launch_bounds__(256) void k2_loss(const float* __restrict__ e,
                                               const float* __restrict__ eT,
                                               const int* __restrict__ mask,
                                               const int* __restrict__ labels,
                                               float* __restrict__ accb) {
  __shared__ float S[16 * LSEQ];  // 64 KB: sims/T for 16 anchors x 1024 cols

  const int tid = threadIdx.x;
  const int b   = blockIdx.x >> 6;
  const int i0  = (blockIdx.x & 63) << 4;

  const float* Ab  = e + ((size_t)(b * LSEQ + i0)) * PDIM;  // uniform base
  const float* ETb = eT + (size_t)b * (PDIM * LSEQ) + tid;

  float s[16][4];
#pragma unroll
  for (int il = 0; il < 16; ++il)
#pragma unroll
    for (int c = 0; c < 4; ++c) s[il][c] = 0.0f;

  for (int k = 0; k < PDIM; k += 4) {
    float ej[4][4];
#pragma unroll
    for (int kk = 0; kk < 4; ++kk)
#pragma unroll
      for (int c = 0; c < 4; ++c)
        ej[kk][c] = ETb[(size_t)(k + kk) * LSEQ + (c << 8)];
#pragma unroll
    for (int il = 0; il < 16; ++il) {
      const float4 a = *(const float4*)(Ab + il * PDIM + k);  // wave-uniform
#pragma unroll
      for (int c = 0; c < 4; ++c) {
        s[il][c] = fmaf(a.x, ej[0][c], s[il][c]);
        s[il][c] = fmaf(a.y, ej[1][c], s[il][c]);
        s[il][c] = fmaf(a.z, ej[2][c], s[il][c]);
        s[il][c] = fmaf(a.w, ej[3][c], s[il][c]);
      }
    }
  }

  const float invT = 1.0f / 0.07f;
#pragma unroll
  for (int il = 0; il < 16; ++il)
#pragma unroll
    for (int c = 0; c < 4; ++c)
      S[il * LSEQ + (c << 8) + tid] = s[il][c] * invT;
  __syncthreads();

  // ---- Pass B: 16 threads per anchor ----
  const int il  = tid >> 4, sub = tid & 15;
  const int ig  = i0 + il;
  const int* mrow = mask + b * LSEQ;
  const int* lrow = labels + b * LSEQ;
  const int li   = lrow[ig];
  const bool validi = (mrow[ig] != 0) && (li != -100);

  unsigned long long cvm = 0ull, samem = 0ull;
  float m = -1e30f;
  for (int q = 0; q < 64; ++q) {
    const int j  = (q << 4) | sub;
    const int lj = lrow[j];
    const bool cvj = (mrow[j] != 0) && (lj != -100);
    if (cvj) {
      cvm |= 1ull << q;
      const float sv = S[il * LSEQ + j];
      m = fmaxf(m, sv);
      if (lj == li) samem |= 1ull << q;
    }
  }
#pragma unroll
  for (int off = 8; off; off >>= 1) m = fmaxf(m, __shfl_xor(m, off, 64));

  unsigned long long cvm2 = cvm;
  if ((ig & 15) == sub) cvm2 &= ~(1ull << (ig >> 4));  // exclude diagonal

  float d = 0.0f, ps = 0.0f;
  float pcf = 0.0f;
  for (int q = 0; q < 64; ++q) {
    if ((cvm2 >> q) & 1ull) {
      const float sv = S[il * LSEQ + ((q << 4) | sub)];
      d += expf(sv - m);
      if (validi && ((samem >> q) & 1ull)) {
        ps += sv;
        pcf += 1.0f;
      }
    }
  }
#pragma unroll
  for (int off = 8; off; off >>= 1) {
    d   += __shfl_xor(d, off, 64);
    ps  += __shfl_xor(ps, off, 64);
    pcf += __shfl_xor(pcf, off, 64);
  }

  if (sub == 0 && validi) {
    const float logD = logf(d + 1e-12f);
    // sum_pos(logits - logD) = ps_raw - n_pos*(m + logD)
    const float al = (ps - pcf * (m + logD)) / (pcf + 1e-12f);
    atomicAdd(&accb[b], al);
  }
}

// ---------------------------------------------------------------------------
// k3: final scalar. 32 lanes per batch count mask/valid; then reduce 32 batches.
// ---------------------------------------------------------------------------
__global__ __launch_bounds__(1024) void k3_final(const int* __restrict__ mask,
                                                 const int* __restrict__ labels,
                                                 const float* __restrict__ accb,
                                                 float* __restrict__ out) {
  __shared__ float lossv[NB];
  __shared__ float okv[NB];
  const int t = threadIdx.x;
  const int b = t >> 5, sub = t & 31;

  int cm = 0, cv = 0;
  for (int q = 0; q < 32; ++q) {
    const int j  = (q << 5) | sub;
    const int mv = mask[b * LSEQ + j];
    const int lv = labels[b * LSEQ + j];
    cm += mv;                              // sum of mask values (0/1)
    cv += (mv != 0 && lv != -100) ? 1 : 0; // valid count
  }
#pragma unroll
  for (int off = 16; off; off >>= 1) {
    cm += __shfl_xor(cm, off, 64);
    cv += __shfl_xor(cv, off, 64);
  }
  if (sub == 0) {
    const bool ok = (cm >= 2);
    lossv[b] = ok ? (-accb[b] / fmaxf((float)cv, 1.0f)) : 0.0f;
    okv[b]   = ok ? 1.0f : 0.0f;
  }
  __syncthreads();
  if (t < NB) {
    float lv = lossv[t], ov = okv[t];
#pragma unroll
    for (int off = 16; off; off >>= 1) {
      lv += __shfl_xor(lv, off, 64);
      ov += __shfl_xor(ov, off, 64);
    }
    if (t == 0) out[0] = lv / fmaxf(ov, 1.0f);
  }
}

// ---------------------------------------------------------------------------
extern "C" void kernel_launch(void* const* d_in, const int* in_sizes, int n_in,
                              void* d_out, int out_size, void* d_ws, size_t ws_size,
                              hipStream_t stream) {
  (void)in_sizes; (void)n_in; (void)out_size; (void)ws_size;
  const float* hs     = (const float*)d_in[0];
  const float* pw     = (const float*)d_in[1];
  const float* pb     = (const float*)d_in[2];
  const int*   mask   = (const int*)d_in[3];
  const int*   labels = (const int*)d_in[4];
  float* out = (float*)d_out;

  float* ws   = (float*)d_ws;
  float* accb = ws + ACC_OFF;
  float* e    = ws + E_OFF;
  float* eT   = ws + ET_OFF;

  hipMemsetAsync(accb, 0, NB * sizeof(float), stream);
  k1_proj<<<(NB * LSEQ) / 16, 128, 0, stream>>>(hs, pw, pb, e, eT);
  k2_loss<<<NB * 64, 256, 0, stream>>>(e, eT, mask, labels, accb);
  k3_final<<<1, 1024, 0, stream>>>(mask, labels, accb, out);
}

// Round 2
// 522.796 us; speedup vs baseline: 2.7171x; 2.7171x over previous
//
#include <hip/hip_runtime.h>
#include <hip/hip_bf16.h>
#include <cstddef>
#include <cstdint>

// Problem dims (fixed by setup_inputs)
#define NB   32
#define LSEQ 1024
#define HDIM 1280
#define PDIM 128

typedef unsigned short ushort_t;
typedef __bf16 bf16x8 __attribute__((ext_vector_type(8)));
typedef float  f32x4  __attribute__((ext_vector_type(4)));

// ws layout (bytes):
//   [0, 128)        : accb (32 floats)
//   [256, 327936)   : wT bf16 [128][1280]
//   [327936, ...)   : e bf16 [32768][128]  (8.4 MB)
#define WT_OFF  256
#define E_OFF   (256 + HDIM * PDIM * 2)

__device__ __forceinline__ ushort_t bf16_rne(float x) {
  unsigned u = __float_as_uint(x);
  unsigned r = u + 0x7fffu + ((u >> 16) & 1u);
  return (ushort_t)(r >> 16);
}

// ---------------------------------------------------------------------------
// k0: wT[n][k] = bf16(w[k][n]).  1280x128 -> tiny.
// ---------------------------------------------------------------------------
__global__ __launch_bounds__(256) void k0_wt(const float* __restrict__ pw,
                                             ushort_t* __restrict__ wT) {
  const int idx = blockIdx.x * 256 + threadIdx.x;  // 0 .. 163839
  const int k = idx >> 7, n = idx & 127;
  wT[(size_t)n * HDIM + k] = bf16_rne(pw[(size_t)k * PDIM + n]);
}

// ---------------------------------------------------------------------------
// k1: e = normalize(hs @ w + b), stored bf16.  MFMA 16x16x32, no LDS.
// Block = 256 thr (4 waves); wave owns 16 rows x 128 cols; K=1280.
// A: hs fp32 -> bf16 in-register (hs read ONCE from HBM).
// B: wT bf16, L2-hot (320 KB total).
// ---------------------------------------------------------------------------
__global__ __launch_bounds__(256) void k1_mfma(const float* __restrict__ hs,
                                               const ushort_t* __restrict__ wT,
                                               const float* __restrict__ pb,
                                               ushort_t* __restrict__ e) {
  const int l  = threadIdx.x & 63;
  const int w  = threadIdx.x >> 6;
  const int m0 = blockIdx.x * 64 + w * 16;
  const int lm = l & 15, lq = l >> 4;

  f32x4 acc[8];
#pragma unroll
  for (int t = 0; t < 8; ++t) acc[t] = (f32x4){0.f, 0.f, 0.f, 0.f};

  float bias[8];
#pragma unroll
  for (int t = 0; t < 8; ++t) bias[t] = pb[t * 16 + lm];

  const float*    arow = hs + (size_t)(m0 + lm) * HDIM + lq * 8;
  const ushort_t* brow = wT + (size_t)lm * HDIM + lq * 8;

#pragma unroll 2
  for (int kc = 0; kc < HDIM; kc += 32) {
    const float4 a0 = *(const float4*)(arow + kc);
    const float4 a1 = *(const float4*)(arow + kc + 4);
    union { bf16x8 v; ushort_t u[8]; } A;
    A.u[0] = bf16_rne(a0.x); A.u[1] = bf16_rne(a0.y);
    A.u[2] = bf16_rne(a0.z); A.u[3] = bf16_rne(a0.w);
    A.u[4] = bf16_rne(a1.x); A.u[5] = bf16_rne(a1.y);
    A.u[6] = bf16_rne(a1.z); A.u[7] = bf16_rne(a1.w);
#pragma unroll
    for (int t = 0; t < 8; ++t) {
      const bf16x8 B = *(const bf16x8*)(brow + (size_t)t * 16 * HDIM + kc);
      acc[t] = __builtin_amdgcn_mfma_f32_16x16x32_bf16(A.v, B, acc[t], 0, 0, 0);
    }
  }

  // bias + row sum-of-squares (row m = lq*4 + r, distributed over 16 lanes)
  float inv[4];
#pragma unroll
  for (int r = 0; r < 4; ++r) {
    float s = 0.f;
#pragma unroll
    for (int t = 0; t < 8; ++t) {
      acc[t][r] += bias[t];
      s = fmaf(acc[t][r], acc[t][r], s);
    }
    s += __shfl_xor(s, 1, 64);
    s += __shfl_xor(s, 2, 64);
    s += __shfl_xor(s, 4, 64);
    s += __shfl_xor(s, 8, 64);
    inv[r] = 1.0f / sqrtf(s);
  }

#pragma unroll
  for (int t = 0; t < 8; ++t)
#pragma unroll
    for (int r = 0; r < 4; ++r)
      e[(size_t)(m0 + lq * 4 + r) * PDIM + t * 16 + lm] =
          bf16_rne(acc[t][r] * inv[r]);
}

// ---------------------------------------------------------------------------
// k2: per (batch, 16-anchor tile): S = (e_i . e_j)/T via MFMA (both operands
// are rows of bf16 e, L2-hot), then masked softmax stats (pass B unchanged).
// ---------------------------------------------------------------------------
__global__ __launch_bounds__(256) void k2_loss(const ushort_t* __restrict__ e,
                                               const int* __restrict__ mask,
                                               const int* __restrict__ labels,
                                               float* __restrict__ accb) {
  __shared__ float S[16 * LSEQ];  // 64 KB

  const int tid = threadIdx.x;
  const int l = tid & 63, w = tid >> 6;
  const int b  = blockIdx.x >> 6;
  const int i0 = (blockIdx.x & 63) << 4;
  const int lm = l & 15, lq = l >> 4;

  const ushort_t* eb = e + (size_t)b * LSEQ * PDIM;

  bf16x8 af[4];
  {
    const ushort_t* aptr = eb + (size_t)(i0 + lm) * PDIM + lq * 8;
#pragma unroll
    for (int c = 0; c < 4; ++c) af[c] = *(const bf16x8*)(aptr + c * 32);
  }

  const float invT = 1.0f / 0.07f;
#pragma unroll 2
  for (int jt = w; jt < 64; jt += 4) {
    const ushort_t* bptr = eb + (size_t)(jt * 16 + lm) * PDIM + lq * 8;
    f32x4 acc = (f32x4){0.f, 0.f, 0.f, 0.f};
#pragma unroll
    for (int c = 0; c < 4; ++c) {
      const bf16x8 B = *(const bf16x8*)(bptr + c * 32);
      acc = __builtin_amdgcn_mfma_f32_16x16x32_bf16(af[c], B, acc, 0, 0, 0);
    }
#pragma unroll
    for (int r = 0; r < 4; ++r)
      S[(lq * 4 + r) * LSEQ + jt * 16 + lm] = acc[r] * invT;
  }
  __syncthreads();

  // ---- Pass B: 16 threads per anchor (verified in round 1) ----
  const int il  = tid >> 4, sub = tid & 15;
  const int ig  = i0 + il;
  const int* mrow = mask + b * LSEQ;
  const int* lrow = labels + b * LSEQ;
  const int li   = lrow[ig];
  const bool validi = (mrow[ig] != 0) && (li != -100);

  unsigned long long cvm = 0ull, samem = 0ull;
  float m = -1e30f;
  for (int q = 0; q < 64; ++q) {
    const int j  = (q << 4) | sub;
    const int lj = lrow[j];
    const bool cvj = (mrow[j] != 0) && (lj != -100);
    if (cvj) {
      cvm |= 1ull << q;
      const float sv = S[il * LSEQ + j];
      m = fmaxf(m, sv);
      if (lj == li) samem |= 1ull << q;
    }
  }
#pragma unroll
  for (int off = 8; off; off >>= 1) m = fmaxf(m, __shfl_xor(m, off, 64));

  unsigned long long cvm2 = cvm;
  if ((ig & 15) == sub) cvm2 &= ~(1ull << (ig >> 4));  // exclude diagonal

  float d = 0.0f, ps = 0.0f, pcf = 0.0f;
  for (int q = 0; q < 64; ++q) {
    if ((cvm2 >> q) & 1ull) {
      const float sv = S[il * LSEQ + ((q << 4) | sub)];
      d += expf(sv - m);
      if (validi && ((samem >> q) & 1ull)) {
        ps += sv;
        pcf += 1.0f;
      }
    }
  }
#pragma unroll
  for (int off = 8; off; off >>= 1) {
    d   += __shfl_xor(d, off, 64);
    ps  += __shfl_xor(ps, off, 64);
    pcf += __shfl_xor(pcf, off, 64);
  }

  if (sub == 0 && validi) {
    const float logD = logf(d + 1e-12f);
    const float al = (ps - pcf * (m + logD)) / (pcf + 1e-12f);
    atomicAdd(&accb[b], al);
  }
}

// ---------------------------------------------------------------------------
// k3: final scalar (unchanged, verified).
// ---------------------------------------------------------------------------
__global__ __launch_bounds__(1024) void k3_final(const int* __restrict__ mask,
                                                 const int* __restrict__ labels,
                                                 const float* __restrict__ accb,
                                                 float* __restrict__ out) {
  __shared__ float lossv[NB];
  __shared__ float okv[NB];
  const int t = threadIdx.x;
  const int b = t >> 5, sub = t & 31;

  int cm = 0, cv = 0;
  for (int q = 0; q < 32; ++q) {
    const int j  = (q << 5) | sub;
    const int mv = mask[b * LSEQ + j];
    const int lv = labels[b * LSEQ + j];
    cm += mv;
    cv += (mv != 0 && lv != -100) ? 1 : 0;
  }
#pragma unroll
  for (int off = 16; off; off >>= 1) {
    cm += __shfl_xor(cm, off, 64);
    cv += __shfl_xor(cv, off, 64);
  }
  if (sub == 0) {
    const bool ok = (cm >= 2);
    lossv[b] = ok ? (-accb[b] / fmaxf((float)cv, 1.0f)) : 0.0f;
    okv[b]   = ok ? 1.0f : 0.0f;
  }
  __syncthreads();
  if (t < NB) {
    float lv = lossv[t], ov = okv[t];
#pragma unroll
    for (int off = 16; off; off >>= 1) {
      lv += __shfl_xor(lv, off, 64);
      ov += __shfl_xor(ov, off, 64);
    }
    if (t == 0) out[0] = lv / fmaxf(ov, 1.0f);
  }
}

// ---------------------------------------------------------------------------
extern "C" void kernel_launch(void* const* d_in, const int* in_sizes, int n_in,
                              void* d_out, int out_size, void* d_ws, size_t ws_size,
                              hipStream_t stream) {
  (void)in_sizes; (void)n_in; (void)out_size; (void)ws_size;
  const float* hs     = (const float*)d_in[0];
  const float* pw     = (const float*)d_in[1];
  const float* pb     = (const float*)d_in[2];
  const int*   mask   = (const int*)d_in[3];
  const int*   labels = (const int*)d_in[4];
  float* out = (float*)d_out;

  char* wsb = (char*)d_ws;
  float*    accb = (float*)wsb;
  ushort_t* wT   = (ushort_t*)(wsb + WT_OFF);
  ushort_t* e    = (ushort_t*)(wsb + E_OFF);

  hipMemsetAsync(accb, 0, NB * sizeof(float), stream);
  k0_wt<<<(HDIM * PDIM) / 256, 256, 0, stream>>>(pw, wT);
  k1_mfma<<<(NB * LSEQ) / 64, 256, 0, stream>>>(hs, wT, pb, e);
  k2_loss<<<NB * 64, 256, 0, stream>>>(e, mask, labels, accb);
  k3_final<<<1, 1024, 0, stream>>>(mask, labels, accb, out);
}

// Round 3
// 375.628 us; speedup vs baseline: 3.7817x; 1.3918x over previous
//
#include <hip/hip_runtime.h>
#include <hip/hip_bf16.h>
#include <cstddef>
#include <cstdint>

// Problem dims (fixed by setup_inputs)
#define NB   32
#define LSEQ 1024
#define HDIM 1280
#define PDIM 128

typedef unsigned short ushort_t;
typedef __bf16 bf16x8 __attribute__((ext_vector_type(8)));
typedef float  f32x4  __attribute__((ext_vector_type(4)));

// ws layout (bytes):
//   [0, 128)      : accb (32 floats)
//   [256, ...)    : wT bf16 [128][1280]
//   [E_OFF, ...)  : e bf16 [32768][128]
#define WT_OFF  256
#define E_OFF   (256 + HDIM * PDIM * 2)

__device__ __forceinline__ ushort_t bf16_rne(float x) {
  unsigned u = __float_as_uint(x);
  unsigned r = u + 0x7fffu + ((u >> 16) & 1u);
  return (ushort_t)(r >> 16);
}

// ---------------------------------------------------------------------------
// k0: wT[n][k] = bf16(w[k][n]).
// ---------------------------------------------------------------------------
__global__ __launch_bounds__(256) void k0_wt(const float* __restrict__ pw,
                                             ushort_t* __restrict__ wT) {
  const int idx = blockIdx.x * 256 + threadIdx.x;
  const int k = idx >> 7, n = idx & 127;
  wT[(size_t)n * HDIM + k] = bf16_rne(pw[(size_t)k * PDIM + n]);
}

// ---------------------------------------------------------------------------
// k1: e = normalize(hs @ w + b), bf16 out. MFMA 16x16x32, no LDS.
// Deep prefetch: double-buffered K=128 groups -> 8 float4 HBM loads in
// flight per lane while the previous group's 32 MFMAs retire.
// ---------------------------------------------------------------------------
__global__ __launch_bounds__(256, 2) void k1_mfma(const float* __restrict__ hs,
                                                  const ushort_t* __restrict__ wT,
                                                  const float* __restrict__ pb,
                                                  ushort_t* __restrict__ e) {
  const int l  = threadIdx.x & 63;
  const int w  = threadIdx.x >> 6;
  const int m0 = blockIdx.x * 64 + w * 16;
  const int lm = l & 15, lq = l >> 4;

  f32x4 acc[8];
#pragma unroll
  for (int t = 0; t < 8; ++t) acc[t] = (f32x4){0.f, 0.f, 0.f, 0.f};

  float bias[8];
#pragma unroll
  for (int t = 0; t < 8; ++t) bias[t] = pb[t * 16 + lm];

  const float*    arow = hs + (size_t)(m0 + lm) * HDIM + lq * 8;
  const ushort_t* brow = wT + (size_t)lm * HDIM + lq * 8;

  float4 Ab[2][8];
#pragma unroll
  for (int c = 0; c < 4; ++c) {
    Ab[0][2 * c]     = *(const float4*)(arow + c * 32);
    Ab[0][2 * c + 1] = *(const float4*)(arow + c * 32 + 4);
  }

#pragma unroll
  for (int g = 0; g < 10; ++g) {
    const int kg = g * 128;
    if (g < 9) {
#pragma unroll
      for (int c = 0; c < 4; ++c) {
        Ab[(g + 1) & 1][2 * c]     = *(const float4*)(arow + kg + 128 + c * 32);
        Ab[(g + 1) & 1][2 * c + 1] = *(const float4*)(arow + kg + 128 + c * 32 + 4);
      }
    }
#pragma unroll
    for (int c = 0; c < 4; ++c) {
      const float4 a0 = Ab[g & 1][2 * c];
      const float4 a1 = Ab[g & 1][2 * c + 1];
      union { bf16x8 v; ushort_t u[8]; } A;
      A.u[0] = bf16_rne(a0.x); A.u[1] = bf16_rne(a0.y);
      A.u[2] = bf16_rne(a0.z); A.u[3] = bf16_rne(a0.w);
      A.u[4] = bf16_rne(a1.x); A.u[5] = bf16_rne(a1.y);
      A.u[6] = bf16_rne(a1.z); A.u[7] = bf16_rne(a1.w);
      const int kc = kg + c * 32;
#pragma unroll
      for (int t = 0; t < 8; ++t) {
        const bf16x8 B = *(const bf16x8*)(brow + (size_t)t * 16 * HDIM + kc);
        acc[t] = __builtin_amdgcn_mfma_f32_16x16x32_bf16(A.v, B, acc[t], 0, 0, 0);
      }
    }
  }

  float inv[4];
#pragma unroll
  for (int r = 0; r < 4; ++r) {
    float s = 0.f;
#pragma unroll
    for (int t = 0; t < 8; ++t) {
      acc[t][r] += bias[t];
      s = fmaf(acc[t][r], acc[t][r], s);
    }
    s += __shfl_xor(s, 1, 64);
    s += __shfl_xor(s, 2, 64);
    s += __shfl_xor(s, 4, 64);
    s += __shfl_xor(s, 8, 64);
    inv[r] = 1.0f / sqrtf(s);
  }

#pragma unroll
  for (int t = 0; t < 8; ++t)
#pragma unroll
    for (int r = 0; r < 4; ++r)
      e[(size_t)(m0 + lq * 4 + r) * PDIM + t * 16 + lm] =
          bf16_rne(acc[t][r] * inv[r]);
}

// ---------------------------------------------------------------------------
// k2: flash-style. Block = (batch, 16-anchor tile); 4 waves split the j
// range (256 j each). Softmax stats accumulate in registers directly from
// the MFMA C-fragment (no S tile, no max-shift: |sv| <= 14.3 so exp is
// safe in fp32; the 1e-12 epsilon difference is O(1e-12)).
// ---------------------------------------------------------------------------
__global__ __launch_bounds__(256, 4) void k2_loss(const ushort_t* __restrict__ e,
                                                  const int* __restrict__ mask,
                                                  const int* __restrict__ labels,
                                                  float* __restrict__ accb) {
  __shared__ float part[4][16][3];

  const int tid = threadIdx.x;
  const int l = tid & 63, w = tid >> 6;
  const int b  = blockIdx.x >> 6;
  const int i0 = (blockIdx.x & 63) << 4;
  const int lm = l & 15, lq = l >> 4;

  const ushort_t* eb   = e + (size_t)b * LSEQ * PDIM;
  const int*      mrow = mask + b * LSEQ;
  const int*      lrow = labels + b * LSEQ;

  bf16x8 af[4];
  {
    const ushort_t* aptr = eb + (size_t)(i0 + lm) * PDIM + lq * 8;
#pragma unroll
    for (int c = 0; c < 4; ++c) af[c] = *(const bf16x8*)(aptr + c * 32);
  }

  int  li[4], ar[4];
  bool vi[4];
#pragma unroll
  for (int r = 0; r < 4; ++r) {
    ar[r] = i0 + lq * 4 + r;
    li[r] = lrow[ar[r]];
    vi[r] = (mrow[ar[r]] != 0) && (li[r] != -100);
  }

  float d[4] = {0.f, 0.f, 0.f, 0.f};
  float ps[4] = {0.f, 0.f, 0.f, 0.f};
  float pc[4] = {0.f, 0.f, 0.f, 0.f};
  const float invT = 1.0f / 0.07f;

#pragma unroll 2
  for (int jt = w * 16; jt < w * 16 + 16; ++jt) {
    const int j = jt * 16 + lm;
    const int lj = lrow[j];
    const int mj = mrow[j];
    const ushort_t* bptr = eb + (size_t)j * PDIM + lq * 8;
    f32x4 acc = (f32x4){0.f, 0.f, 0.f, 0.f};
#pragma unroll
    for (int c = 0; c < 4; ++c) {
      const bf16x8 B = *(const bf16x8*)(bptr + c * 32);
      acc = __builtin_amdgcn_mfma_f32_16x16x32_bf16(af[c], B, acc, 0, 0, 0);
    }
    const bool cvj = (mj != 0) && (lj != -100);
#pragma unroll
    for (int r = 0; r < 4; ++r) {
      const float sv = acc[r] * invT;
      const bool dm  = cvj && (j != ar[r]);
      const float ex = __expf(sv);
      d[r] += dm ? ex : 0.f;
      const bool pos = dm && (lj == li[r]) && vi[r];
      ps[r] += pos ? sv : 0.f;
      pc[r] += pos ? 1.f : 0.f;
    }
  }

#pragma unroll
  for (int r = 0; r < 4; ++r) {
#pragma unroll
    for (int off = 1; off < 16; off <<= 1) {
      d[r]  += __shfl_xor(d[r], off, 64);
      ps[r] += __shfl_xor(ps[r], off, 64);
      pc[r] += __shfl_xor(pc[r], off, 64);
    }
  }
  if (lm == 0) {
#pragma unroll
    for (int r = 0; r < 4; ++r) {
      part[w][lq * 4 + r][0] = d[r];
      part[w][lq * 4 + r][1] = ps[r];
      part[w][lq * 4 + r][2] = pc[r];
    }
  }
  __syncthreads();

  if (tid < 16) {
    float D = 0.f, P = 0.f, C = 0.f;
#pragma unroll
    for (int w2 = 0; w2 < 4; ++w2) {
      D += part[w2][tid][0];
      P += part[w2][tid][1];
      C += part[w2][tid][2];
    }
    const float logD = logf(D + 1e-12f);
    float al = (P - C * logD) / (C + 1e-12f);
#pragma unroll
    for (int off = 1; off < 16; off <<= 1) al += __shfl_xor(al, off, 64);
    if (tid == 0) atomicAdd(&accb[b], al);
  }
}

// ---------------------------------------------------------------------------
// k3: final scalar (unchanged, verified).
// ---------------------------------------------------------------------------
__global__ __launch_bounds__(1024) void k3_final(const int* __restrict__ mask,
                                                 const int* __restrict__ labels,
                                                 const float* __restrict__ accb,
                                                 float* __restrict__ out) {
  __shared__ float lossv[NB];
  __shared__ float okv[NB];
  const int t = threadIdx.x;
  const int b = t >> 5, sub = t & 31;

  int cm = 0, cv = 0;
  for (int q = 0; q < 32; ++q) {
    const int j  = (q << 5) | sub;
    const int mv = mask[b * LSEQ + j];
    const int lv = labels[b * LSEQ + j];
    cm += mv;
    cv += (mv != 0 && lv != -100) ? 1 : 0;
  }
#pragma unroll
  for (int off = 16; off; off >>= 1) {
    cm += __shfl_xor(cm, off, 64);
    cv += __shfl_xor(cv, off, 64);
  }
  if (sub == 0) {
    const bool ok = (cm >= 2);
    lossv[b] = ok ? (-accb[b] / fmaxf((float)cv, 1.0f)) : 0.0f;
    okv[b]   = ok ? 1.0f : 0.0f;
  }
  __syncthreads();
  if (t < NB) {
    float lv = lossv[t], ov = okv[t];
#pragma unroll
    for (int off = 16; off; off >>= 1) {
      lv += __shfl_xor(lv, off, 64);
      ov += __shfl_xor(ov, off, 64);
    }
    if (t == 0) out[0] = lv / fmaxf(ov, 1.0f);
  }
}

// ---------------------------------------------------------------------------
extern "C" void kernel_launch(void* const* d_in, const int* in_sizes, int n_in,
                              void* d_out, int out_size, void* d_ws, size_t ws_size,
                              hipStream_t stream) {
  (void)in_sizes; (void)n_in; (void)out_size; (void)ws_size;
  const float* hs     = (const float*)d_in[0];
  const float* pw     = (const float*)d_in[1];
  const float* pb     = (const float*)d_in[2];
  const int*   mask   = (const int*)d_in[3];
  const int*   labels = (const int*)d_in[4];
  float* out = (float*)d_out;

  char* wsb = (char*)d_ws;
  float*    accb = (float*)wsb;
  ushort_t* wT   = (ushort_t*)(wsb + WT_OFF);
  ushort_t* e    = (ushort_t*)(wsb + E_OFF);

  hipMemsetAsync(accb, 0, NB * sizeof(float), stream);
  k0_wt<<<(HDIM * PDIM) / 256, 256, 0, stream>>>(pw, wT);
  k1_mfma<<<(NB * LSEQ) / 64, 256, 0, stream>>>(hs, wT, pb, e);
  k2_loss<<<NB * 64, 256, 0, stream>>>(e, mask, labels, accb);
  k3_final<<<1, 1024, 0, stream>>>(mask, labels, accb, out);
}

// Round 4
// 368.196 us; speedup vs baseline: 3.8580x; 1.0202x over previous
//
#include <hip/hip_runtime.h>
#include <hip/hip_bf16.h>
#include <cstddef>
#include <cstdint>

// Problem dims (fixed by setup_inputs)
#define NB   32
#define LSEQ 1024
#define HDIM 1280
#define PDIM 128

typedef unsigned short ushort_t;
typedef __bf16 bf16x8 __attribute__((ext_vector_type(8)));
typedef float  f32x4  __attribute__((ext_vector_type(4)));

// ws layout (bytes):
//   [0, 128)      : accb (32 floats)
//   [256, ...)    : wT bf16 [128][1280]
//   [E_OFF, ...)  : e bf16 [32768][128]
#define WT_OFF  256
#define E_OFF   (256 + HDIM * PDIM * 2)

__device__ __forceinline__ ushort_t bf16_rne(float x) {
  unsigned u = __float_as_uint(x);
  unsigned r = u + 0x7fffu + ((u >> 16) & 1u);
  return (ushort_t)(r >> 16);
}

// ---------------------------------------------------------------------------
// k0: wT[n][k] = bf16(w[k][n]); block 0 also zeroes accb (replaces memset).
// ---------------------------------------------------------------------------
__global__ __launch_bounds__(256) void k0_wt(const float* __restrict__ pw,
                                             ushort_t* __restrict__ wT,
                                             float* __restrict__ accb) {
  if (blockIdx.x == 0 && threadIdx.x < NB) accb[threadIdx.x] = 0.0f;
  const int idx = blockIdx.x * 256 + threadIdx.x;
  const int k = idx >> 7, n = idx & 127;
  wT[(size_t)n * HDIM + k] = bf16_rne(pw[(size_t)k * PDIM + n]);
}

// ---------------------------------------------------------------------------
// k1: e = normalize(hs @ w + b), bf16 out.  MFMA 16x16x32.
// A staged fp32 via global_load_lds (width 16, async DMA, no VGPR round
// trip), double-buffered 64x64 tiles, BK=64, 20 barrier-paced iters.
// Staging of tile k+1 is issued before computing tile k, so the vmcnt
// queue holds a full 16 KB tile while the barrier drains -> HBM-BW-paced.
// ---------------------------------------------------------------------------
__device__ __forceinline__ void stage_tile(const float* __restrict__ src,
                                           float* lds, int w, int l) {
#pragma unroll
  for (int i = 0; i < 4; ++i) {
    const int s = w * 4 + i;  // segment = 4 rows x 64 floats = 1 KB per wave-call
    const float* g = src + (size_t)(s * 4 + (l >> 4)) * HDIM + (l & 15) * 4;
    __builtin_amdgcn_global_load_lds(
        (const __attribute__((address_space(1))) void*)g,
        (__attribute__((address_space(3))) void*)(lds + s * 256),
        16, 0, 0);
  }
}

__global__ __launch_bounds__(256, 2) void k1_mfma(const float* __restrict__ hs,
                                                  const ushort_t* __restrict__ wT,
                                                  const float* __restrict__ pb,
                                                  ushort_t* __restrict__ e) {
  __shared__ float At[2][64 * 64];  // 2 x 16 KB

  const int tid = threadIdx.x;
  const int l = tid & 63, w = tid >> 6;
  const int lm = l & 15, lq = l >> 4;
  const int m0 = blockIdx.x * 64;

  f32x4 acc[8];
#pragma unroll
  for (int t = 0; t < 8; ++t) acc[t] = (f32x4){0.f, 0.f, 0.f, 0.f};

  float bias[8];
#pragma unroll
  for (int t = 0; t < 8; ++t) bias[t] = pb[t * 16 + lm];

  const ushort_t* brow = wT + (size_t)lm * HDIM + lq * 8;
  const float*    asrc = hs + (size_t)m0 * HDIM;

  stage_tile(asrc, &At[0][0], w, l);
  __syncthreads();

#pragma unroll 1
  for (int it = 0; it < 20; ++it) {
    const int cur = it & 1;
    if (it < 19) stage_tile(asrc + (it + 1) * 64, &At[cur ^ 1][0], w, l);
#pragma unroll
    for (int half = 0; half < 2; ++half) {
      const float* ap = &At[cur][(16 * w + lm) * 64 + half * 32 + lq * 8];
      const float4 a0 = *(const float4*)ap;
      const float4 a1 = *(const float4*)(ap + 4);
      union { bf16x8 v; ushort_t u[8]; } A;
      A.u[0] = bf16_rne(a0.x); A.u[1] = bf16_rne(a0.y);
      A.u[2] = bf16_rne(a0.z); A.u[3] = bf16_rne(a0.w);
      A.u[4] = bf16_rne(a1.x); A.u[5] = bf16_rne(a1.y);
      A.u[6] = bf16_rne(a1.z); A.u[7] = bf16_rne(a1.w);
      const int kc = it * 64 + half * 32;
#pragma unroll
      for (int t = 0; t < 8; ++t) {
        const bf16x8 B = *(const bf16x8*)(brow + (size_t)t * 16 * HDIM + kc);
        acc[t] = __builtin_amdgcn_mfma_f32_16x16x32_bf16(A.v, B, acc[t], 0, 0, 0);
      }
    }
    __syncthreads();
  }

  // bias + row norm (row m = 16w + lq*4 + r, distributed over 16 lanes)
  float inv[4];
#pragma unroll
  for (int r = 0; r < 4; ++r) {
    float s = 0.f;
#pragma unroll
    for (int t = 0; t < 8; ++t) {
      acc[t][r] += bias[t];
      s = fmaf(acc[t][r], acc[t][r], s);
    }
    s += __shfl_xor(s, 1, 64);
    s += __shfl_xor(s, 2, 64);
    s += __shfl_xor(s, 4, 64);
    s += __shfl_xor(s, 8, 64);
    inv[r] = 1.0f / sqrtf(s);
  }

#pragma unroll
  for (int t = 0; t < 8; ++t)
#pragma unroll
    for (int r = 0; r < 4; ++r)
      e[(size_t)(m0 + 16 * w + lq * 4 + r) * PDIM + t * 16 + lm] =
          bf16_rne(acc[t][r] * inv[r]);
}

// ---------------------------------------------------------------------------
// k2: flash-style. Block = (batch, 16-anchor tile); 4 waves split the j
// range. Softmax stats accumulate in registers off the MFMA C-fragment
// (no S tile; |sv| <= 14.3 so unshifted exp is fp32-safe).
// ---------------------------------------------------------------------------
__global__ __launch_bounds__(256, 4) void k2_loss(const ushort_t* __restrict__ e,
                                                  const int* __restrict__ mask,
                                                  const int* __restrict__ labels,
                                                  float* __restrict__ accb) {
  __shared__ float part[4][16][3];

  const int tid = threadIdx.x;
  const int l = tid & 63, w = tid >> 6;
  const int b  = blockIdx.x >> 6;
  const int i0 = (blockIdx.x & 63) << 4;
  const int lm = l & 15, lq = l >> 4;

  const ushort_t* eb   = e + (size_t)b * LSEQ * PDIM;
  const int*      mrow = mask + b * LSEQ;
  const int*      lrow = labels + b * LSEQ;

  bf16x8 af[4];
  {
    const ushort_t* aptr = eb + (size_t)(i0 + lm) * PDIM + lq * 8;
#pragma unroll
    for (int c = 0; c < 4; ++c) af[c] = *(const bf16x8*)(aptr + c * 32);
  }

  int  li[4], ar[4];
  bool vi[4];
#pragma unroll
  for (int r = 0; r < 4; ++r) {
    ar[r] = i0 + lq * 4 + r;
    li[r] = lrow[ar[r]];
    vi[r] = (mrow[ar[r]] != 0) && (li[r] != -100);
  }

  float d[4] = {0.f, 0.f, 0.f, 0.f};
  float ps[4] = {0.f, 0.f, 0.f, 0.f};
  float pc[4] = {0.f, 0.f, 0.f, 0.f};
  const float invT = 1.0f / 0.07f;

#pragma unroll 2
  for (int jt = w * 16; jt < w * 16 + 16; ++jt) {
    const int j = jt * 16 + lm;
    const int lj = lrow[j];
    const int mj = mrow[j];
    const ushort_t* bptr = eb + (size_t)j * PDIM + lq * 8;
    f32x4 acc = (f32x4){0.f, 0.f, 0.f, 0.f};
#pragma unroll
    for (int c = 0; c < 4; ++c) {
      const bf16x8 B = *(const bf16x8*)(bptr + c * 32);
      acc = __builtin_amdgcn_mfma_f32_16x16x32_bf16(af[c], B, acc, 0, 0, 0);
    }
    const bool cvj = (mj != 0) && (lj != -100);
#pragma unroll
    for (int r = 0; r < 4; ++r) {
      const float sv = acc[r] * invT;
      const bool dm  = cvj && (j != ar[r]);
      const float ex = __expf(sv);
      d[r] += dm ? ex : 0.f;
      const bool pos = dm && (lj == li[r]) && vi[r];
      ps[r] += pos ? sv : 0.f;
      pc[r] += pos ? 1.f : 0.f;
    }
  }

#pragma unroll
  for (int r = 0; r < 4; ++r) {
#pragma unroll
    for (int off = 1; off < 16; off <<= 1) {
      d[r]  += __shfl_xor(d[r], off, 64);
      ps[r] += __shfl_xor(ps[r], off, 64);
      pc[r] += __shfl_xor(pc[r], off, 64);
    }
  }
  if (lm == 0) {
#pragma unroll
    for (int r = 0; r < 4; ++r) {
      part[w][lq * 4 + r][0] = d[r];
      part[w][lq * 4 + r][1] = ps[r];
      part[w][lq * 4 + r][2] = pc[r];
    }
  }
  __syncthreads();

  if (tid < 16) {
    float D = 0.f, P = 0.f, C = 0.f;
#pragma unroll
    for (int w2 = 0; w2 < 4; ++w2) {
      D += part[w2][tid][0];
      P += part[w2][tid][1];
      C += part[w2][tid][2];
    }
    const float logD = logf(D + 1e-12f);
    float al = (P - C * logD) / (C + 1e-12f);
#pragma unroll
    for (int off = 1; off < 16; off <<= 1) al += __shfl_xor(al, off, 64);
    if (tid == 0) atomicAdd(&accb[b], al);
  }
}

// ---------------------------------------------------------------------------
// k3: final scalar (unchanged, verified).
// ---------------------------------------------------------------------------
__global__ __launch_bounds__(1024) void k3_final(const int* __restrict__ mask,
                                                 const int* __restrict__ labels,
                                                 const float* __restrict__ accb,
                                                 float* __restrict__ out) {
  __shared__ float lossv[NB];
  __shared__ float okv[NB];
  const int t = threadIdx.x;
  const int b = t >> 5, sub = t & 31;

  int cm = 0, cv = 0;
  for (int q = 0; q < 32; ++q) {
    const int j  = (q << 5) | sub;
    const int mv = mask[b * LSEQ + j];
    const int lv = labels[b * LSEQ + j];
    cm += mv;
    cv += (mv != 0 && lv != -100) ? 1 : 0;
  }
#pragma unroll
  for (int off = 16; off; off >>= 1) {
    cm += __shfl_xor(cm, off, 64);
    cv += __shfl_xor(cv, off, 64);
  }
  if (sub == 0) {
    const bool ok = (cm >= 2);
    lossv[b] = ok ? (-accb[b] / fmaxf((float)cv, 1.0f)) : 0.0f;
    okv[b]   = ok ? 1.0f : 0.0f;
  }
  __syncthreads();
  if (t < NB) {
    float lv = lossv[t], ov = okv[t];
#pragma unroll
    for (int off = 16; off; off >>= 1) {
      lv += __shfl_xor(lv, off, 64);
      ov += __shfl_xor(ov, off, 64);
    }
    if (t == 0) out[0] = lv / fmaxf(ov, 1.0f);
  }
}

// ---------------------------------------------------------------------------
extern "C" void kernel_launch(void* const* d_in, const int* in_sizes, int n_in,
                              void* d_out, int out_size, void* d_ws, size_t ws_size,
                              hipStream_t stream) {
  (void)in_sizes; (void)n_in; (void)out_size; (void)ws_size;
  const float* hs     = (const float*)d_in[0];
  const float* pw     = (const float*)d_in[1];
  const float* pb     = (const float*)d_in[2];
  const int*   mask   = (const int*)d_in[3];
  const int*   labels = (const int*)d_in[4];
  float* out = (float*)d_out;

  char* wsb = (char*)d_ws;
  float*    accb = (float*)wsb;
  ushort_t* wT   = (ushort_t*)(wsb + WT_OFF);
  ushort_t* e    = (ushort_t*)(wsb + E_OFF);

  k0_wt<<<(HDIM * PDIM) / 256, 256, 0, stream>>>(pw, wT, accb);
  k1_mfma<<<(NB * LSEQ) / 64, 256, 0, stream>>>(hs, wT, pb, e);
  k2_loss<<<NB * 64, 256, 0, stream>>>(e, mask, labels, accb);
  k3_final<<<1, 1024, 0, stream>>>(mask, labels, accb, out);
}